// Round 7
// baseline (837.869 us; speedup 1.0000x reference)
//
#include <hip/hip_runtime.h>
#include <hip/hip_bf16.h>
#include <math.h>

// Problem constants: N=100000, E=3200000, F_IN=512, H=16, C=40
#define F_IN 512
#define H 16
#define COUT 40               // compile-time class count

// ---------------- CSR build: node histogram -> scan -> direct scatter ----------------
// Replaces the old 2-level LDS-staged scatter (scat1/scat2/pass2): that chain cost
// ~8 contended LDS atomics per edge (~32-128-way same-address serialization) and
// ~350-400us total (R3/R4 cross-round arithmetic). Direct build: 2 uncontended
// global atomics per edge, edges land in final sorted position immediately.

__global__ __launch_bounds__(256) void hist2_kernel(const int* __restrict__ col,
                                                    int* __restrict__ ncnt, int E) {
    int i = (blockIdx.x * 256 + threadIdx.x) * 4;
    if (i + 4 <= E) {
        int4 c = *(const int4*)&col[i];
        atomicAdd(&ncnt[c.x], 1);
        atomicAdd(&ncnt[c.y], 1);
        atomicAdd(&ncnt[c.z], 1);
        atomicAdd(&ncnt[c.w], 1);
    } else {
        for (; i < E; ++i) atomicAdd(&ncnt[col[i]], 1);
    }
}

// block-local exclusive scan of ncnt (1024/block) -> rowptr partial, block sums
__global__ void scanA_kernel(const int* __restrict__ ncnt, int* __restrict__ rowptr,
                             int* __restrict__ bsum, int N) {
    __shared__ int sm[1024];
    int t = threadIdx.x, n = blockIdx.x * 1024 + t;
    int v = (n < N) ? ncnt[n] : 0;
    sm[t] = v;
    __syncthreads();
    for (int o = 1; o < 1024; o <<= 1) {
        int u = (t >= o) ? sm[t - o] : 0;
        __syncthreads();
        sm[t] += u;
        __syncthreads();
    }
    if (n < N) rowptr[n] = sm[t] - v;       // block-local exclusive
    if (t == 1023) bsum[blockIdx.x] = sm[t];
}

// exclusive scan of block sums (nsb <= 128) in place
__global__ void scanB_kernel(int* __restrict__ bsum, int nsb) {
    __shared__ int sm[128];
    int t = threadIdx.x;
    int v = (t < nsb) ? bsum[t] : 0;
    sm[t] = v;
    __syncthreads();
    for (int o = 1; o < 128; o <<= 1) {
        int u = (t >= o) ? sm[t - o] : 0;
        __syncthreads();
        sm[t] += u;
        __syncthreads();
    }
    if (t < nsb) bsum[t] = sm[t] - v;
}

__global__ __launch_bounds__(256) void scanC_kernel(int* __restrict__ rowptr,
                                                    const int* __restrict__ bsum,
                                                    int N, int E) {
    int n = blockIdx.x * 256 + threadIdx.x;
    if (n < N) rowptr[n] += bsum[n >> 10];
    if (n == N) rowptr[N] = E;
}

// direct scatter to final sorted slot: packed[rowptr[col]+rank] = {row, ew}
__global__ __launch_bounds__(256) void scatter_kernel(const int* __restrict__ row,
                                                      const int* __restrict__ col,
                                                      const float* __restrict__ ew,
                                                      const int* __restrict__ rowptr,
                                                      int* __restrict__ fill,
                                                      int2* __restrict__ packed, int E) {
    int i = (blockIdx.x * 256 + threadIdx.x) * 4;
    if (i + 4 <= E) {
        int4 c = *(const int4*)&col[i];
        int4 r = *(const int4*)&row[i];
        float4 w = *(const float4*)&ew[i];
        int b0 = rowptr[c.x], b1 = rowptr[c.y], b2 = rowptr[c.z], b3 = rowptr[c.w];
        int k0 = atomicAdd(&fill[c.x], 1);
        int k1 = atomicAdd(&fill[c.y], 1);
        int k2 = atomicAdd(&fill[c.z], 1);
        int k3 = atomicAdd(&fill[c.w], 1);
        packed[b0 + k0] = make_int2(r.x, __float_as_int(w.x));
        packed[b1 + k1] = make_int2(r.y, __float_as_int(w.y));
        packed[b2 + k2] = make_int2(r.z, __float_as_int(w.z));
        packed[b3 + k3] = make_int2(r.w, __float_as_int(w.w));
    } else {
        for (; i < E; ++i) {
            int c = col[i];
            int k = atomicAdd(&fill[c], 1);
            packed[rowptr[c] + k] = make_int2(row[i], __float_as_int(ew[i]));
        }
    }
}

// dinv[n] = rsqrt(1 + sum of ew over node n's sorted edges)
__global__ __launch_bounds__(256) void dinv_kernel(const int* __restrict__ rowptr,
                                                   const int2* __restrict__ packed,
                                                   float* __restrict__ dinv, int N) {
    int n = blockIdx.x * 256 + threadIdx.x;
    if (n >= N) return;
    int s = rowptr[n], e = rowptr[n + 1];
    float sum = 1.0f;   // self-loop weight 1
    for (int i = s; i < e; ++i) sum += __int_as_float(packed[i].y);
    dinv[n] = rsqrtf(sum);
}

// ---------------- layer 1: g0 = dinv * relu(x @ W_first + b_first) ----------------
// R3/R6-measured form (~79us). R4 direct-global broadcast: 197us (latency-bound).
// R5 O=2 LDS blocking: ~106us. LDS-read-BW-bound at ~61us model floor.

#define L1_ROWS 8
#define XS_CH 36
#define XS_ROW (16 * XS_CH)

__global__ __launch_bounds__(256) void l1_kernel(const float* __restrict__ x,
                                                 const float* __restrict__ W,
                                                 const float* __restrict__ b,
                                                 const float* __restrict__ dinv,
                                                 float* __restrict__ g0, int N) {
    __shared__ float xs[L1_ROWS][XS_ROW];
    __shared__ float part[L1_ROWS][256];
    const int t  = threadIdx.x;
    const int o  = t & 15;
    const int fg = t >> 4;

    float Wreg[32];
#pragma unroll
    for (int j = 0; j < 32; ++j) Wreg[j] = W[(fg * 32 + j) * H + o];
    const float bias = b[o];

    const int nbatch = (N + L1_ROWS - 1) / L1_ROWS;
    for (int batch = blockIdx.x; batch < nbatch; batch += gridDim.x) {
        const int row0 = batch * L1_ROWS;
#pragma unroll
        for (int bq = 0; bq < 4; ++bq) {
            int L  = bq * 256 + t;
            int rl = L >> 7;
            int f4 = L & 127;
            int r  = row0 + rl;
            float4 v = make_float4(0.f, 0.f, 0.f, 0.f);
            if (r < N) v = *(const float4*)&x[(size_t)r * F_IN + f4 * 4];
            int fgs = f4 >> 3, j4 = f4 & 7;
            *(float4*)&xs[rl][fgs * XS_CH + j4 * 4] = v;
        }
        __syncthreads();

        float acc[L1_ROWS];
#pragma unroll
        for (int r = 0; r < L1_ROWS; ++r) acc[r] = 0.f;
#pragma unroll
        for (int j4 = 0; j4 < 8; ++j4) {
#pragma unroll
            for (int r = 0; r < L1_ROWS; ++r) {
                float4 xv = *(const float4*)&xs[r][fg * XS_CH + j4 * 4];
                acc[r] = fmaf(xv.x, Wreg[j4 * 4 + 0], acc[r]);
                acc[r] = fmaf(xv.y, Wreg[j4 * 4 + 1], acc[r]);
                acc[r] = fmaf(xv.z, Wreg[j4 * 4 + 2], acc[r]);
                acc[r] = fmaf(xv.w, Wreg[j4 * 4 + 3], acc[r]);
            }
        }
#pragma unroll
        for (int r = 0; r < L1_ROWS; ++r) part[r][fg * 16 + o] = acc[r];
        __syncthreads();

        if (t < 128) {
            int r = t >> 4, oo = t & 15;
            float s = 0.f;
#pragma unroll
            for (int g = 0; g < 16; ++g) s += part[r][g * 16 + oo];
            s = fmaxf(s + bias, 0.f);
            int rr = row0 + r;
            if (rr < N) g0[(size_t)rr * H + oo] = s * dinv[rr];
        }
        __syncthreads();
    }
}

// ---------------- fused conv layer ----------------
// Input g = dinv-scaled activations. Per node i:
//   y_i = dinv_i * (g_i + sum_{edges j->i} ew * g_j)          (16-wide, lane-parallel)
//   h_i = relu(y_i @ Wc + bc)                                  (cross-lane shfl transform)
// LAST=0: write g' = dinv_i * h_i       (next layer's scaled input)
// LAST=1: logits = h_i @ Wo + bo; write log_softmax(logits)    (in-register, shfl reduce)
// Edge loop is 4-wide with loads batched ahead of FMAs (MLP for the
// latency-bound random g reads).

template<bool LAST>
__global__ __launch_bounds__(256) void conv_kernel(const int* __restrict__ rowptr,
                                                   const int2* __restrict__ packed,
                                                   const float* __restrict__ g_in,
                                                   const float* __restrict__ dinv,
                                                   const float* __restrict__ Wc,
                                                   const float* __restrict__ bc,
                                                   const float* __restrict__ Wo,
                                                   const float* __restrict__ bo,
                                                   float* __restrict__ out, int N) {
    __shared__ float Wcs[H * H];
    __shared__ float bcs[H];
    __shared__ float Wos[H * 48];   // zero-padded columns 40..47
    __shared__ float bos[48];
    const int tt = threadIdx.x;
    if (tt < H * H) Wcs[tt] = Wc[tt];
    if (tt < H) bcs[tt] = bc[tt];
    if (LAST) {
        for (int i = tt; i < H * 48; i += 256) {
            int f = i / 48, c = i % 48;
            Wos[i] = (c < COUT) ? Wo[f * COUT + c] : 0.f;
        }
        if (tt < 48) bos[tt] = (tt < COUT) ? bo[tt] : 0.f;
    }
    __syncthreads();

    int t = blockIdx.x * 256 + tt;
    int n = t >> 4, o = t & 15;
    if (n >= N) return;

    int s = rowptr[n], e = rowptr[n + 1];
    float acc = g_in[(size_t)n * H + o];  // self-loop term
    int i = s;
    for (; i + 4 <= e; i += 4) {
        int2 p0 = packed[i],     p1 = packed[i + 1];
        int2 p2 = packed[i + 2], p3 = packed[i + 3];
        float h0 = g_in[(size_t)p0.x * H + o];
        float h1 = g_in[(size_t)p1.x * H + o];
        float h2 = g_in[(size_t)p2.x * H + o];
        float h3 = g_in[(size_t)p3.x * H + o];
        acc = fmaf(__int_as_float(p0.y), h0, acc);
        acc = fmaf(__int_as_float(p1.y), h1, acc);
        acc = fmaf(__int_as_float(p2.y), h2, acc);
        acc = fmaf(__int_as_float(p3.y), h3, acc);
    }
    for (; i < e; ++i) {
        int2 p = packed[i];
        acc = fmaf(__int_as_float(p.y), g_in[(size_t)p.x * H + o], acc);
    }
    const float di = dinv[n];
    const float y = di * acc;

    // h = relu(bc[o] + sum_f y_f * Wc[f][o]) via cross-lane within 16-lane group
    float h = bcs[o];
#pragma unroll
    for (int f = 0; f < H; ++f) {
        float yf = __shfl(y, f, 16);
        h = fmaf(yf, Wcs[f * H + o], h);
    }
    h = fmaxf(h, 0.f);

    if (!LAST) {
        out[(size_t)n * H + o] = di * h;
    } else {
        float l0 = bos[o], l1 = bos[o + 16], l2 = bos[o + 32];
#pragma unroll
        for (int f = 0; f < H; ++f) {
            float hf = __shfl(h, f, 16);
            l0 = fmaf(hf, Wos[f * 48 + o], l0);
            l1 = fmaf(hf, Wos[f * 48 + o + 16], l1);
            l2 = fmaf(hf, Wos[f * 48 + o + 32], l2);   // padded zeros for o>=8
        }
        float m = fmaxf(l0, l1);
        if (o < 8) m = fmaxf(m, l2);
#pragma unroll
        for (int d = 1; d < 16; d <<= 1) m = fmaxf(m, __shfl_xor(m, d, 16));
        float sx = __expf(l0 - m) + __expf(l1 - m) + ((o < 8) ? __expf(l2 - m) : 0.f);
#pragma unroll
        for (int d = 1; d < 16; d <<= 1) sx += __shfl_xor(sx, d, 16);
        float lse = m + __logf(sx);
        out[(size_t)n * COUT + o]      = l0 - lse;
        out[(size_t)n * COUT + o + 16] = l1 - lse;
        if (o < 8) out[(size_t)n * COUT + o + 32] = l2 - lse;
    }
}

// ---------------- launch ----------------

extern "C" void kernel_launch(void* const* d_in, const int* in_sizes, int n_in,
                              void* d_out, int out_size, void* d_ws, size_t ws_size,
                              hipStream_t stream) {
    const float* x       = (const float*)d_in[0];
    const int*   ei      = (const int*)d_in[1];
    const float* ew      = (const float*)d_in[2];
    const float* W_first = (const float*)d_in[3];
    const float* b_first = (const float*)d_in[4];
    const float* W_c1    = (const float*)d_in[5];
    const float* b_c1    = (const float*)d_in[6];
    const float* W_c2    = (const float*)d_in[7];
    const float* b_c2    = (const float*)d_in[8];
    const float* W_o     = (const float*)d_in[9];
    const float* b_o     = (const float*)d_in[10];

    const int N = in_sizes[0] / F_IN;
    const int E = in_sizes[2];

    const int* row = ei;      // edge_index[0] = source
    const int* col = ei + E;  // edge_index[1] = target

    const int NB1024 = (N + 1023) / 1024;           // 98 scan blocks (<=128)
    const int GB4    = (E / 4 + 255) / 256;         // 4-edge-per-thread grids

    char* wsb = (char*)d_ws;
    int*   ncnt   = (int*)wsb;                  wsb += (size_t)N * 4;
    int*   fill   = (int*)wsb;                  wsb += (size_t)N * 4;   // contiguous w/ ncnt for one memset
    int*   rowptr = (int*)wsb;                  wsb += (size_t)(N + 1) * 4;
    int*   bsum   = (int*)wsb;                  wsb += (size_t)128 * 4;
    float* dinv   = (float*)wsb;                wsb += (size_t)N * 4;
    int2*  packed = (int2*)wsb;                 wsb += (size_t)E * 8;
    float* g0     = (float*)wsb;                wsb += (size_t)N * H * 4;
    float* g1     = (float*)wsb;                wsb += (size_t)N * H * 4;

    // zero ncnt + fill (contiguous)
    hipMemsetAsync(ncnt, 0, (size_t)2 * N * 4, stream);

    // CSR build: node histogram -> 3-step scan -> direct sorted scatter -> dinv
    hist2_kernel<<<GB4, 256, 0, stream>>>(col, ncnt, E);
    scanA_kernel<<<NB1024, 1024, 0, stream>>>(ncnt, rowptr, bsum, N);
    scanB_kernel<<<1, 128, 0, stream>>>(bsum, NB1024);
    scanC_kernel<<<(N + 256) / 256, 256, 0, stream>>>(rowptr, bsum, N, E);
    scatter_kernel<<<GB4, 256, 0, stream>>>(row, col, ew, rowptr, fill, packed, E);
    dinv_kernel<<<(N + 255) / 256, 256, 0, stream>>>(rowptr, packed, dinv, N);

    // layer 1 -> g0 (dinv-scaled)
    l1_kernel<<<1024, 256, 0, stream>>>(x, W_first, b_first, dinv, g0, N);

    // conv1 (fused aggregate + 16x16 transform) -> g1
    conv_kernel<false><<<(N * 16 + 255) / 256, 256, 0, stream>>>(
        rowptr, packed, g0, dinv, W_c1, b_c1, nullptr, nullptr, g1, N);

    // conv2 + output layer + log_softmax, fully fused -> d_out
    conv_kernel<true><<<(N * 16 + 255) / 256, 256, 0, stream>>>(
        rowptr, packed, g1, dinv, W_c2, b_c2, W_o, b_o, (float*)d_out, N);
}

// Round 8
// 573.343 us; speedup vs baseline: 1.4614x; 1.4614x over previous
//
#include <hip/hip_runtime.h>
#include <hip/hip_bf16.h>
#include <math.h>

// Problem constants: N=100000, E=3200000, F_IN=512, H=16, C=40
#define F_IN 512
#define H 16
#define COUT 40               // compile-time class count
#define BSH 7                 // final bucket: 128 nodes
#define BNODES (1 << BSH)
#define SSH 12                // super bucket: 4096 nodes (32 final buckets)
#define EPT 64                // edges per thread in hist
#define CAP 5376              // max edges per final bucket in pass2 LDS
#define SEG 4096              // edges staged per scat block
#define SL 33                 // slices per super in scat2

// LEDGER (do not re-try): R4 l1 direct-global broadcast = 197us (latency-bound).
// R5 l1 O=2 blocking = ~106us (reduce doubling ate savings). R7 direct random
// scatter = 290us (8.7x write-amp, WRITE_SIZE 222MB vs 25.6MB logical).
// Two-level LDS staging wins BECAUSE it coalesces the scattered writes.

// ---------------- hist: global histogram of 782 final buckets ----------------

__global__ __launch_bounds__(256) void hist_kernel(const int* __restrict__ col,
                                                   int* __restrict__ bcnt, int E, int NBUCK) {
    extern __shared__ int hs[];  // NBUCK ints
    const int t = threadIdx.x;
    for (int i = t; i < NBUCK; i += 256) hs[i] = 0;
    __syncthreads();
    long long e0 = (long long)blockIdx.x * (256 * EPT) + t;
#pragma unroll 4
    for (int k = 0; k < EPT; ++k) {
        long long e = e0 + (long long)k * 256;
        if (e < E) atomicAdd(&hs[col[e] >> BSH], 1);
    }
    __syncthreads();
    for (int i = t; i < NBUCK; i += 256) {
        int h = hs[i];
        if (h > 0) atomicAdd(&bcnt[i], h);
    }
}

// 1 block, 1024 threads: exclusive scan -> bbase[782], sbase[nsup+1], rowptr[N]=E
__global__ void bscan_kernel(const int* __restrict__ bcnt, int* __restrict__ bbase,
                             int* __restrict__ sbase, int* __restrict__ rowptr,
                             int NBUCK, int nsup, int E, int N) {
    __shared__ int sm[1024];
    int t = threadIdx.x;
    int v = (t < NBUCK) ? bcnt[t] : 0;
    sm[t] = v;
    __syncthreads();
    for (int o = 1; o < 1024; o <<= 1) {
        int u = (t >= o) ? sm[t - o] : 0;
        __syncthreads();
        sm[t] += u;
        __syncthreads();
    }
    if (t < NBUCK) bbase[t] = sm[t] - v;
    if (t == 0) { bbase[NBUCK] = E; rowptr[N] = E; }
    __syncthreads();
    if (t < nsup) {
        int bk = t << (SSH - BSH);
        sbase[t] = (bk < NBUCK) ? (sm[bk] - bcnt[bk]) : E;
    }
    if (t == nsup) sbase[nsup] = E;
}

// ---------------- scat1: edges -> 25 super buckets (LDS-staged) ----------------
// payload: x = row | (col & 4095) << 17  (29 bits), y = ew bits

__global__ __launch_bounds__(256) void scat1_kernel(const int* __restrict__ row,
                                                    const int* __restrict__ col,
                                                    const float* __restrict__ ew,
                                                    const int* __restrict__ sbase,
                                                    int* __restrict__ sfill,
                                                    int2* __restrict__ ptmp, int E, int nsup) {
    __shared__ int2 stg[SEG];          // 32 KB
    __shared__ unsigned char sup[SEG]; // 4 KB
    __shared__ int cnt[32], base[32];
    const int t = threadIdx.x;
    const int e0 = blockIdx.x * SEG;
    int m = E - e0; if (m > SEG) m = SEG;
    if (t < 32) cnt[t] = 0;
    __syncthreads();
    for (int i = t; i < m; i += 256) {
        int e = e0 + i;
        int c = col[e];
        int s = c >> SSH;
        sup[i] = (unsigned char)s;
        atomicAdd(&cnt[s], 1);
        stg[i] = make_int2(row[e] | ((c & ((1 << SSH) - 1)) << 17), __float_as_int(ew[e]));
    }
    __syncthreads();
    if (t < nsup) {
        int h = cnt[t];
        base[t] = h ? atomicAdd(&sfill[t], h) : 0;
        cnt[t] = 0;
    }
    __syncthreads();
    for (int i = t; i < m; i += 256) {
        int s = sup[i];
        int rk = atomicAdd(&cnt[s], 1);
        ptmp[sbase[s] + base[s] + rk] = stg[i];
    }
}

// ---------------- scat2: super bucket slices -> 32 final buckets each ----------------

__global__ __launch_bounds__(256) void scat2_kernel(const int* __restrict__ sbase,
                                                    const int* __restrict__ bbase,
                                                    int* __restrict__ ffill,
                                                    const int2* __restrict__ ptmp,
                                                    int2* __restrict__ packed, int NBUCK) {
    __shared__ int2 stg[SEG];   // 32 KB
    __shared__ int cnt[32], base[32];
    const int t = threadIdx.x;
    const int s  = blockIdx.x / SL;
    const int sl = blockIdx.x % SL;
    const int ss = sbase[s];
    const int len = sbase[s + 1] - ss;
    const int lo = ss + (int)((long long)len * sl / SL);
    const int hi = ss + (int)((long long)len * (sl + 1) / SL);
    int m = hi - lo; if (m > SEG) m = SEG;  // statistically impossible overflow clamp
    if (t < 32) cnt[t] = 0;
    __syncthreads();
    for (int i = t; i < m; i += 256) {
        int2 p = ptmp[lo + i];
        stg[i] = p;
        int bk5 = ((unsigned)p.x >> (17 + BSH)) & 31;  // (col&4095)>>7
        atomicAdd(&cnt[bk5], 1);
    }
    __syncthreads();
    if (t < 32) {
        int bk = (s << 5) + t;
        int h = cnt[t];
        base[t] = (h && bk < NBUCK) ? atomicAdd(&ffill[bk], h) : 0;
        cnt[t] = 0;
    }
    __syncthreads();
    for (int i = t; i < m; i += 256) {
        int2 p = stg[i];
        int bk5 = ((unsigned)p.x >> (17 + BSH)) & 31;
        int rk = atomicAdd(&cnt[bk5], 1);
        int bk = (s << 5) + bk5;
        // final payload: row (17b) | lcol (7b) << 17
        packed[bbase[bk] + base[bk5] + rk] = make_int2(p.x & 0xFFFFFF, p.y);
    }
}

// One block per final bucket: stage edges in LDS, per-node count/scan, rewrite
// bucket in place fully sorted; emit rowptr and dinv for the bucket's nodes.
__global__ __launch_bounds__(256) void pass2_kernel(const int* __restrict__ bbase,
                                                    int2* __restrict__ packed,
                                                    int* __restrict__ rowptr,
                                                    float* __restrict__ dinv, int N) {
    __shared__ int2  edg[CAP];
    __shared__ int   ncnt[BNODES], nsc[BNODES], nfill[BNODES];
    __shared__ float dsum[BNODES];
    const int t = threadIdx.x;
    const int b = blockIdx.x;
    const int s = bbase[b];
    int cnt = bbase[b + 1] - s;
    if (cnt > CAP) cnt = CAP;

    for (int i = t; i < cnt; i += 256) edg[i] = packed[s + i];
    if (t < BNODES) { ncnt[t] = 0; nfill[t] = 0; dsum[t] = 0.f; }
    __syncthreads();

    for (int i = t; i < cnt; i += 256) {
        int lc = (edg[i].x >> 17) & (BNODES - 1);
        atomicAdd(&ncnt[lc], 1);
        atomicAdd(&dsum[lc], __int_as_float(edg[i].y));
    }
    __syncthreads();
    if (t < BNODES) nsc[t] = ncnt[t];
    __syncthreads();
    for (int o = 1; o < BNODES; o <<= 1) {
        int v = (t < BNODES && t >= o) ? nsc[t - o] : 0;
        __syncthreads();
        if (t < BNODES) nsc[t] += v;
        __syncthreads();
    }
    if (t < BNODES) {
        int n = b * BNODES + t;
        if (n < N) {
            rowptr[n] = s + nsc[t] - ncnt[t];
            dinv[n]   = rsqrtf(1.0f + dsum[t]);   // self-loop weight 1
        }
    }
    __syncthreads();
    for (int i = t; i < cnt; i += 256) {
        int lc = (edg[i].x >> 17) & (BNODES - 1);
        int rk = atomicAdd(&nfill[lc], 1);
        packed[s + nsc[lc] - ncnt[lc] + rk] = make_int2(edg[i].x & 0x1FFFF, edg[i].y);
    }
}

// ---------------- layer 1: g0 = dinv * relu(x @ W_first + b_first) ----------------
// R3/R6-measured form (~79us).

#define L1_ROWS 8
#define XS_CH 36
#define XS_ROW (16 * XS_CH)

__global__ __launch_bounds__(256) void l1_kernel(const float* __restrict__ x,
                                                 const float* __restrict__ W,
                                                 const float* __restrict__ b,
                                                 const float* __restrict__ dinv,
                                                 float* __restrict__ g0, int N) {
    __shared__ float xs[L1_ROWS][XS_ROW];
    __shared__ float part[L1_ROWS][256];
    const int t  = threadIdx.x;
    const int o  = t & 15;
    const int fg = t >> 4;

    float Wreg[32];
#pragma unroll
    for (int j = 0; j < 32; ++j) Wreg[j] = W[(fg * 32 + j) * H + o];
    const float bias = b[o];

    const int nbatch = (N + L1_ROWS - 1) / L1_ROWS;
    for (int batch = blockIdx.x; batch < nbatch; batch += gridDim.x) {
        const int row0 = batch * L1_ROWS;
#pragma unroll
        for (int bq = 0; bq < 4; ++bq) {
            int L  = bq * 256 + t;
            int rl = L >> 7;
            int f4 = L & 127;
            int r  = row0 + rl;
            float4 v = make_float4(0.f, 0.f, 0.f, 0.f);
            if (r < N) v = *(const float4*)&x[(size_t)r * F_IN + f4 * 4];
            int fgs = f4 >> 3, j4 = f4 & 7;
            *(float4*)&xs[rl][fgs * XS_CH + j4 * 4] = v;
        }
        __syncthreads();

        float acc[L1_ROWS];
#pragma unroll
        for (int r = 0; r < L1_ROWS; ++r) acc[r] = 0.f;
#pragma unroll
        for (int j4 = 0; j4 < 8; ++j4) {
#pragma unroll
            for (int r = 0; r < L1_ROWS; ++r) {
                float4 xv = *(const float4*)&xs[r][fg * XS_CH + j4 * 4];
                acc[r] = fmaf(xv.x, Wreg[j4 * 4 + 0], acc[r]);
                acc[r] = fmaf(xv.y, Wreg[j4 * 4 + 1], acc[r]);
                acc[r] = fmaf(xv.z, Wreg[j4 * 4 + 2], acc[r]);
                acc[r] = fmaf(xv.w, Wreg[j4 * 4 + 3], acc[r]);
            }
        }
#pragma unroll
        for (int r = 0; r < L1_ROWS; ++r) part[r][fg * 16 + o] = acc[r];
        __syncthreads();

        if (t < 128) {
            int r = t >> 4, oo = t & 15;
            float s = 0.f;
#pragma unroll
            for (int g = 0; g < 16; ++g) s += part[r][g * 16 + oo];
            s = fmaxf(s + bias, 0.f);
            int rr = row0 + r;
            if (rr < N) g0[(size_t)rr * H + oo] = s * dinv[rr];
        }
        __syncthreads();
    }
}

// ---------------- fused conv layer ----------------
// Input g = dinv-scaled activations. Per node i:
//   y_i = dinv_i * (g_i + sum_{edges j->i} ew * g_j)          (16-wide, lane-parallel)
//   h_i = relu(y_i @ Wc + bc)                                  (cross-lane shfl transform)
// LAST=0: write g' = dinv_i * h_i       (next layer's scaled input)
// LAST=1: logits = h_i @ Wo + bo; write log_softmax(logits)    (in-register, shfl reduce)
// Edge loop is 4-wide with loads batched ahead of FMAs (MLP for the
// latency-bound random g reads).

template<bool LAST>
__global__ __launch_bounds__(256) void conv_kernel(const int* __restrict__ rowptr,
                                                   const int2* __restrict__ packed,
                                                   const float* __restrict__ g_in,
                                                   const float* __restrict__ dinv,
                                                   const float* __restrict__ Wc,
                                                   const float* __restrict__ bc,
                                                   const float* __restrict__ Wo,
                                                   const float* __restrict__ bo,
                                                   float* __restrict__ out, int N) {
    __shared__ float Wcs[H * H];
    __shared__ float bcs[H];
    __shared__ float Wos[H * 48];   // zero-padded columns 40..47
    __shared__ float bos[48];
    const int tt = threadIdx.x;
    if (tt < H * H) Wcs[tt] = Wc[tt];
    if (tt < H) bcs[tt] = bc[tt];
    if (LAST) {
        for (int i = tt; i < H * 48; i += 256) {
            int f = i / 48, c = i % 48;
            Wos[i] = (c < COUT) ? Wo[f * COUT + c] : 0.f;
        }
        if (tt < 48) bos[tt] = (tt < COUT) ? bo[tt] : 0.f;
    }
    __syncthreads();

    int t = blockIdx.x * 256 + tt;
    int n = t >> 4, o = t & 15;
    if (n >= N) return;

    int s = rowptr[n], e = rowptr[n + 1];
    float acc = g_in[(size_t)n * H + o];  // self-loop term
    int i = s;
    for (; i + 4 <= e; i += 4) {
        int2 p0 = packed[i],     p1 = packed[i + 1];
        int2 p2 = packed[i + 2], p3 = packed[i + 3];
        float h0 = g_in[(size_t)p0.x * H + o];
        float h1 = g_in[(size_t)p1.x * H + o];
        float h2 = g_in[(size_t)p2.x * H + o];
        float h3 = g_in[(size_t)p3.x * H + o];
        acc = fmaf(__int_as_float(p0.y), h0, acc);
        acc = fmaf(__int_as_float(p1.y), h1, acc);
        acc = fmaf(__int_as_float(p2.y), h2, acc);
        acc = fmaf(__int_as_float(p3.y), h3, acc);
    }
    for (; i < e; ++i) {
        int2 p = packed[i];
        acc = fmaf(__int_as_float(p.y), g_in[(size_t)p.x * H + o], acc);
    }
    const float di = dinv[n];
    const float y = di * acc;

    // h = relu(bc[o] + sum_f y_f * Wc[f][o]) via cross-lane within 16-lane group
    float h = bcs[o];
#pragma unroll
    for (int f = 0; f < H; ++f) {
        float yf = __shfl(y, f, 16);
        h = fmaf(yf, Wcs[f * H + o], h);
    }
    h = fmaxf(h, 0.f);

    if (!LAST) {
        out[(size_t)n * H + o] = di * h;
    } else {
        float l0 = bos[o], l1 = bos[o + 16], l2 = bos[o + 32];
#pragma unroll
        for (int f = 0; f < H; ++f) {
            float hf = __shfl(h, f, 16);
            l0 = fmaf(hf, Wos[f * 48 + o], l0);
            l1 = fmaf(hf, Wos[f * 48 + o + 16], l1);
            l2 = fmaf(hf, Wos[f * 48 + o + 32], l2);   // padded zeros for o>=8
        }
        float m = fmaxf(l0, l1);
        if (o < 8) m = fmaxf(m, l2);
#pragma unroll
        for (int d = 1; d < 16; d <<= 1) m = fmaxf(m, __shfl_xor(m, d, 16));
        float sx = __expf(l0 - m) + __expf(l1 - m) + ((o < 8) ? __expf(l2 - m) : 0.f);
#pragma unroll
        for (int d = 1; d < 16; d <<= 1) sx += __shfl_xor(sx, d, 16);
        float lse = m + __logf(sx);
        out[(size_t)n * COUT + o]      = l0 - lse;
        out[(size_t)n * COUT + o + 16] = l1 - lse;
        if (o < 8) out[(size_t)n * COUT + o + 32] = l2 - lse;
    }
}

// ---------------- launch ----------------

extern "C" void kernel_launch(void* const* d_in, const int* in_sizes, int n_in,
                              void* d_out, int out_size, void* d_ws, size_t ws_size,
                              hipStream_t stream) {
    const float* x       = (const float*)d_in[0];
    const int*   ei      = (const int*)d_in[1];
    const float* ew      = (const float*)d_in[2];
    const float* W_first = (const float*)d_in[3];
    const float* b_first = (const float*)d_in[4];
    const float* W_c1    = (const float*)d_in[5];
    const float* b_c1    = (const float*)d_in[6];
    const float* W_c2    = (const float*)d_in[7];
    const float* b_c2    = (const float*)d_in[8];
    const float* W_o     = (const float*)d_in[9];
    const float* b_o     = (const float*)d_in[10];

    const int N = in_sizes[0] / F_IN;
    const int E = in_sizes[2];
    const int NBUCK = (N + BNODES - 1) >> BSH;            // 782
    const int NSUP  = ((N - 1) >> SSH) + 1;               // 25
    const int HB    = (E + 256 * EPT - 1) / (256 * EPT);  // 196
    const int SB    = (E + SEG - 1) / SEG;                // 782

    const int* row = ei;      // edge_index[0] = source
    const int* col = ei + E;  // edge_index[1] = target

    char* wsb = (char*)d_ws;
    int*   bcnt   = (int*)wsb;                  wsb += (size_t)NBUCK * 4;
    int*   sfill  = (int*)wsb;                  wsb += (size_t)32 * 4;
    int*   ffill  = (int*)wsb;                  wsb += (size_t)NBUCK * 4;
    int*   bbase  = (int*)wsb;                  wsb += (size_t)(NBUCK + 1) * 4;
    int*   sbase  = (int*)wsb;                  wsb += (size_t)(NSUP + 1) * 4;
    int*   rowptr = (int*)wsb;                  wsb += (size_t)(N + 1) * 4;
    float* dinv   = (float*)wsb;                wsb += (size_t)N * 4;
    int2*  packed = (int2*)wsb;                 wsb += (size_t)E * 8;
    int2*  ptmp   = (int2*)wsb;                 wsb += (size_t)E * 8;
    // ptmp is dead after scat2; reuse it for the two activation buffers
    float* g0     = (float*)ptmp;                         // N*H floats
    float* g1     = (float*)ptmp + (size_t)N * H;         // N*H floats

    // zero bcnt + sfill + ffill (contiguous)
    hipMemsetAsync(bcnt, 0, (size_t)(NBUCK * 2 + 32) * 4, stream);

    // CSR build: hist -> scan -> super scatter -> final scatter -> node sort
    hist_kernel<<<HB, 256, NBUCK * 4, stream>>>(col, bcnt, E, NBUCK);
    bscan_kernel<<<1, 1024, 0, stream>>>(bcnt, bbase, sbase, rowptr, NBUCK, NSUP, E, N);
    scat1_kernel<<<SB, 256, 0, stream>>>(row, col, ew, sbase, sfill, ptmp, E, NSUP);
    scat2_kernel<<<NSUP * SL, 256, 0, stream>>>(sbase, bbase, ffill, ptmp, packed, NBUCK);
    pass2_kernel<<<NBUCK, 256, 0, stream>>>(bbase, packed, rowptr, dinv, N);

    // layer 1 -> g0 (dinv-scaled)
    l1_kernel<<<1024, 256, 0, stream>>>(x, W_first, b_first, dinv, g0, N);

    // conv1 (fused aggregate + 16x16 transform) -> g1
    conv_kernel<false><<<(N * 16 + 255) / 256, 256, 0, stream>>>(
        rowptr, packed, g0, dinv, W_c1, b_c1, nullptr, nullptr, g1, N);

    // conv2 + output layer + log_softmax, fully fused -> d_out
    conv_kernel<true><<<(N * 16 + 255) / 256, 256, 0, stream>>>(
        rowptr, packed, g1, dinv, W_c2, b_c2, W_o, b_o, (float*)d_out, N);
}